// Round 4
// baseline (78.287 us; speedup 1.0000x reference)
//
#include <hip/hip_runtime.h>

#define BOLTZMAN 0.001987191f

__device__ __forceinline__ float rowdot(const float4 a, const float4 b,
                                        const float4 x, const float4 y) {
    return a.x * x.x + a.y * x.y + a.z * x.z + a.w * x.w
         + b.x * y.x + b.y * y.y + b.z * y.z + b.w * y.w;
}

// Fused single kernel: each block recomputes the 128 coefficients into LDS
// (wave 0 only, ~500 cycles, hidden under memory waits), then runs the
// round-1 streaming body: 16 lanes per row, lane c loads one aligned float4
// at column 4c of v_list/w_list (wave = 1 KiB contiguous per instruction),
// shfl_xor tree-reduce over the 16-lane group, lane 0 writes.
//
// Coefficients (folding sign/scale/reversal; ring slot 0 is dead and carries
// the newest-sample coefficient):
//   A[t] = -scale*mk[64-t] (t>=1), A[0] = -scale*mk[0]   -> multiplies v_list / v
//   B[t] =  h[64-t]        (t>=1), B[0] =  h[0]          -> multiplies w_list / w_new
//   mk[lag] = autocorrelation of h, scale = mass[0]*kB*T.
__global__ void __launch_bounds__(256) gle_fused(
    const float* __restrict__ v, const float* __restrict__ w_new,
    const float* __restrict__ v_list, const float* __restrict__ w_list,
    const float* __restrict__ h, const float* __restrict__ mass,
    const int* __restrict__ T, float* __restrict__ out, int nrows)
{
    __shared__ float sh[64];
    __shared__ float scoef[128];   // A[0..63], B[0..63]

    const int tid = threadIdx.x;
    if (tid < 64) sh[tid] = h[tid];
    __syncthreads();
    if (tid < 64) {
        float scale = mass[0] * BOLTZMAN * (float)T[0];
        int lag = (tid == 0) ? 0 : (64 - tid);
        float s = 0.0f;
        for (int k = 0; k + lag < 64; ++k) s += sh[k] * sh[k + lag];
        scoef[tid]      = -scale * s;                        // A[tid]
        scoef[64 + tid] = (tid == 0) ? sh[0] : sh[64 - tid]; // B[tid]
    }
    __syncthreads();

    const int row = blockIdx.x * 16 + (tid >> 4);
    const int c = tid & 15;
    if (row >= nrows) return;

    const float4 a = ((const float4*)scoef)[c];
    const float4 b = ((const float4*)(scoef + 64))[c];

    float4 x = ((const float4*)(v_list + (size_t)row * 64))[c];
    float4 y = ((const float4*)(w_list + (size_t)row * 64))[c];
    if (c == 0) { x.x = v[row]; y.x = w_new[row]; }  // ring slot 0 is dead

    float s = rowdot(a, b, x, y);

    s += __shfl_xor(s, 1);
    s += __shfl_xor(s, 2);
    s += __shfl_xor(s, 4);
    s += __shfl_xor(s, 8);

    if (c == 0) out[row] = s;
}

extern "C" void kernel_launch(void* const* d_in, const int* in_sizes, int n_in,
                              void* d_out, int out_size, void* d_ws, size_t ws_size,
                              hipStream_t stream) {
    const float* v      = (const float*)d_in[0];   // [N,3] f32
    const int*   T      = (const int*)d_in[1];     // scalar int
    /* d_in[2] = dt (unused) */
    const float* mass   = (const float*)d_in[3];   // [N,3] f32 (use [0])
    const float* h      = (const float*)d_in[4];   // [1,1,64] f32
    const float* v_list = (const float*)d_in[5];   // [3N,1,64] f32
    const float* w_list = (const float*)d_in[6];   // [3N,1,64] f32
    const float* w_new  = (const float*)d_in[7];   // [N,3] f32
    float* out  = (float*)d_out;                   // [N,3] f32

    int nrows = in_sizes[0];                       // 3N = 600000

    int blocks = (nrows + 15) / 16;                // 16 rows per 256-thread block
    gle_fused<<<blocks, 256, 0, stream>>>(v, w_new, v_list, w_list,
                                          h, mass, T, out, nrows);
}

// Round 5
// 58.627 us; speedup vs baseline: 1.3353x; 1.3353x over previous
//
#include <hip/hip_runtime.h>

#define BOLTZMAN 0.001987191f
#define ROWS_PER_BLOCK 32

__device__ __forceinline__ float rowdot(const float4 a, const float4 b,
                                        const float4 x, const float4 y) {
    return a.x * x.x + a.y * x.y + a.z * x.z + a.w * x.w
         + b.x * y.x + b.y * y.y + b.z * y.z + b.w * y.w;
}

// Single fused kernel, NO __syncthreads. Each wave builds the 128
// coefficients in a wave-private LDS slice (same-wave ds_write->ds_read is
// ordered by the wave's own instruction stream + lgkmcnt; wave_barrier pins
// compiler ordering). The stream float4 loads are issued BEFORE the ~700cy
// coefficient loop so it hides under their HBM latency.
//
// Coefficients (sign/scale/reversal folded; ring slot 0 is dead and carries
// the newest-sample coefficient):
//   A[t] = -scale*mk[64-t] (t>=1), A[0] = -scale*mk[0]   -> v_list / v
//   B[t] =  h[64-t]        (t>=1), B[0] =  h[0]          -> w_list / w_new
//   mk[lag] = autocorrelation of h, scale = mass[0]*kB*T.
__global__ void __launch_bounds__(256) gle_fused(
    const float* __restrict__ v, const float* __restrict__ w_new,
    const float* __restrict__ v_list, const float* __restrict__ w_list,
    const float* __restrict__ h, const float* __restrict__ mass,
    const int* __restrict__ T, float* __restrict__ out, int nrows)
{
    __shared__ float sh_h[4][64];      // wave-private h copy
    __shared__ float sh_coef[4][128];  // wave-private A[0..63], B[0..63]

    const int tid  = threadIdx.x;
    const int wid  = tid >> 6;         // wave id 0..3
    const int lane = tid & 63;
    const int c    = tid & 15;         // 16 lanes per row
    const int base = blockIdx.x * ROWS_PER_BLOCK;

    // ---- issue both batches' stream loads up front (latency cover) ----
    const int r0 = base + (tid >> 4);       // batch 0: rows base..base+15
    const int r1 = r0 + 16;                 // batch 1: rows base+16..base+31
    float4 x0, y0, x1, y1;
    bool ok0 = r0 < nrows, ok1 = r1 < nrows;
    if (ok0) {
        x0 = ((const float4*)(v_list + (size_t)r0 * 64))[c];
        y0 = ((const float4*)(w_list + (size_t)r0 * 64))[c];
    }
    if (ok1) {
        x1 = ((const float4*)(v_list + (size_t)r1 * 64))[c];
        y1 = ((const float4*)(w_list + (size_t)r1 * 64))[c];
    }

    // ---- per-wave coefficient build (overlaps the loads above) ----
    sh_h[wid][lane] = h[lane];
    float scale = mass[0] * BOLTZMAN * (float)T[0];
    __builtin_amdgcn_wave_barrier();
    {
        int lag = (lane == 0) ? 0 : (64 - lane);
        float s = 0.0f;
        // k is a uniform-valued counter: sh_h[wid][k] broadcasts (no conflict);
        // sh_h[wid][k+lag] is stride-1 across lanes (2-way max = free).
        for (int k = 0; k + lag < 64; ++k)
            s += sh_h[wid][k] * sh_h[wid][k + lag];
        sh_coef[wid][lane]      = -scale * s;                          // A
        sh_coef[wid][64 + lane] = (lane == 0) ? sh_h[wid][0]
                                              : sh_h[wid][64 - lane];  // B
    }
    __builtin_amdgcn_wave_barrier();
    const float4 a = ((const float4*)sh_coef[wid])[c];
    const float4 b = ((const float4*)(sh_coef[wid] + 64))[c];

    // ---- batch 0 ----
    if (ok0) {
        if (c == 0) { x0.x = v[r0]; y0.x = w_new[r0]; }  // ring slot 0 dead
        float s = rowdot(a, b, x0, y0);
        #pragma unroll
        for (int m = 1; m <= 8; m <<= 1) s += __shfl_xor(s, m);
        if (c == 0) out[r0] = s;
    }
    // ---- batch 1 ----
    if (ok1) {
        if (c == 0) { x1.x = v[r1]; y1.x = w_new[r1]; }
        float s = rowdot(a, b, x1, y1);
        #pragma unroll
        for (int m = 1; m <= 8; m <<= 1) s += __shfl_xor(s, m);
        if (c == 0) out[r1] = s;
    }
}

extern "C" void kernel_launch(void* const* d_in, const int* in_sizes, int n_in,
                              void* d_out, int out_size, void* d_ws, size_t ws_size,
                              hipStream_t stream) {
    const float* v      = (const float*)d_in[0];   // [N,3] f32
    const int*   T      = (const int*)d_in[1];     // scalar int
    /* d_in[2] = dt (unused) */
    const float* mass   = (const float*)d_in[3];   // [N,3] f32 (use [0])
    const float* h      = (const float*)d_in[4];   // [1,1,64] f32
    const float* v_list = (const float*)d_in[5];   // [3N,1,64] f32
    const float* w_list = (const float*)d_in[6];   // [3N,1,64] f32
    const float* w_new  = (const float*)d_in[7];   // [N,3] f32
    float* out  = (float*)d_out;                   // [N,3] f32

    int nrows = in_sizes[0];                       // 3N = 600000

    int blocks = (nrows + ROWS_PER_BLOCK - 1) / ROWS_PER_BLOCK;  // 18750
    gle_fused<<<blocks, 256, 0, stream>>>(v, w_new, v_list, w_list,
                                          h, mass, T, out, nrows);
}

// Round 6
// 52.744 us; speedup vs baseline: 1.4843x; 1.1115x over previous
//
#include <hip/hip_runtime.h>

#define BOLTZMAN 0.001987191f
#define ROWS_PER_BLOCK 64   // 4 batches of 16 rows; block spans 16 KB/buffer

__device__ __forceinline__ float rowdot(const float4 a, const float4 b,
                                        const float4 x, const float4 y) {
    return a.x * x.x + a.y * x.y + a.z * x.z + a.w * x.w
         + b.x * y.x + b.y * y.y + b.z * y.z + b.w * y.w;
}

// Single fused kernel, NO __syncthreads. Each wave builds the 128
// coefficients in a wave-private LDS slice (same-wave ds_write->ds_read is
// ordered by the wave's instruction stream + lgkmcnt; wave_barrier pins
// compiler ordering). All 8 stream float4 loads are issued BEFORE the
// coefficient loop so it hides under their HBM latency; the build cost is
// amortized over 64 rows/block (2x round 5).
//
// Coefficients (sign/scale/reversal folded; ring slot 0 is dead and carries
// the newest-sample coefficient):
//   A[t] = -scale*mk[64-t] (t>=1), A[0] = -scale*mk[0]   -> v_list / v
//   B[t] =  h[64-t]        (t>=1), B[0] =  h[0]          -> w_list / w_new
//   mk[lag] = autocorrelation of h, scale = mass[0]*kB*T.
__global__ void __launch_bounds__(256) gle_fused(
    const float* __restrict__ v, const float* __restrict__ w_new,
    const float* __restrict__ v_list, const float* __restrict__ w_list,
    const float* __restrict__ h, const float* __restrict__ mass,
    const int* __restrict__ T, float* __restrict__ out, int nrows)
{
    __shared__ float sh_h[4][64];      // wave-private h copy
    __shared__ float sh_coef[4][128];  // wave-private A[0..63], B[0..63]

    const int tid  = threadIdx.x;
    const int wid  = tid >> 6;         // wave id 0..3
    const int lane = tid & 63;
    const int c    = tid & 15;         // 16 lanes per row
    const int base = blockIdx.x * ROWS_PER_BLOCK;
    const int rr   = base + (tid >> 4);        // batch-0 row for this thread
    const bool fast = (base + ROWS_PER_BLOCK) <= nrows;

    // ---- fast path: issue all 4 batches' stream loads up front ----
    float4 x0, y0, x1, y1, x2, y2, x3, y3;
    if (fast) {
        x0 = ((const float4*)(v_list + (size_t)(rr     ) * 64))[c];
        y0 = ((const float4*)(w_list + (size_t)(rr     ) * 64))[c];
        x1 = ((const float4*)(v_list + (size_t)(rr + 16) * 64))[c];
        y1 = ((const float4*)(w_list + (size_t)(rr + 16) * 64))[c];
        x2 = ((const float4*)(v_list + (size_t)(rr + 32) * 64))[c];
        y2 = ((const float4*)(w_list + (size_t)(rr + 32) * 64))[c];
        x3 = ((const float4*)(v_list + (size_t)(rr + 48) * 64))[c];
        y3 = ((const float4*)(w_list + (size_t)(rr + 48) * 64))[c];
    }

    // ---- per-wave coefficient build (overlaps the loads above) ----
    sh_h[wid][lane] = h[lane];
    float scale = mass[0] * BOLTZMAN * (float)T[0];
    __builtin_amdgcn_wave_barrier();
    {
        int lag = (lane == 0) ? 0 : (64 - lane);
        float s = 0.0f;
        // sh_h[wid][k] broadcasts (uniform k); sh_h[wid][k+lag] is stride-1
        // across lanes (2-way max = free).
        for (int k = 0; k + lag < 64; ++k)
            s += sh_h[wid][k] * sh_h[wid][k + lag];
        sh_coef[wid][lane]      = -scale * s;                          // A
        sh_coef[wid][64 + lane] = (lane == 0) ? sh_h[wid][0]
                                              : sh_h[wid][64 - lane];  // B
    }
    __builtin_amdgcn_wave_barrier();
    const float4 a = ((const float4*)sh_coef[wid])[c];
    const float4 b = ((const float4*)(sh_coef[wid] + 64))[c];

    if (fast) {
        if (c == 0) {                          // ring slot 0 is dead
            x0.x = v[rr];      y0.x = w_new[rr];
            x1.x = v[rr + 16]; y1.x = w_new[rr + 16];
            x2.x = v[rr + 32]; y2.x = w_new[rr + 32];
            x3.x = v[rr + 48]; y3.x = w_new[rr + 48];
        }
        float s0 = rowdot(a, b, x0, y0);
        float s1 = rowdot(a, b, x1, y1);
        float s2 = rowdot(a, b, x2, y2);
        float s3 = rowdot(a, b, x3, y3);
        #pragma unroll
        for (int m = 1; m <= 8; m <<= 1) {     // 4 independent reduce chains
            s0 += __shfl_xor(s0, m);
            s1 += __shfl_xor(s1, m);
            s2 += __shfl_xor(s2, m);
            s3 += __shfl_xor(s3, m);
        }
        if (c == 0) {
            out[rr]      = s0;
            out[rr + 16] = s1;
            out[rr + 32] = s2;
            out[rr + 48] = s3;
        }
    } else {
        // ---- tail path: per-batch guarded loop ----
        #pragma unroll
        for (int i = 0; i < 4; ++i) {
            int r = rr + 16 * i;
            if (r < nrows) {
                float4 x = ((const float4*)(v_list + (size_t)r * 64))[c];
                float4 y = ((const float4*)(w_list + (size_t)r * 64))[c];
                if (c == 0) { x.x = v[r]; y.x = w_new[r]; }
                float s = rowdot(a, b, x, y);
                #pragma unroll
                for (int m = 1; m <= 8; m <<= 1) s += __shfl_xor(s, m);
                if (c == 0) out[r] = s;
            }
        }
    }
}

extern "C" void kernel_launch(void* const* d_in, const int* in_sizes, int n_in,
                              void* d_out, int out_size, void* d_ws, size_t ws_size,
                              hipStream_t stream) {
    const float* v      = (const float*)d_in[0];   // [N,3] f32
    const int*   T      = (const int*)d_in[1];     // scalar int
    /* d_in[2] = dt (unused) */
    const float* mass   = (const float*)d_in[3];   // [N,3] f32 (use [0])
    const float* h      = (const float*)d_in[4];   // [1,1,64] f32
    const float* v_list = (const float*)d_in[5];   // [3N,1,64] f32
    const float* w_list = (const float*)d_in[6];   // [3N,1,64] f32
    const float* w_new  = (const float*)d_in[7];   // [N,3] f32
    float* out  = (float*)d_out;                   // [N,3] f32

    int nrows = in_sizes[0];                       // 3N = 600000

    int blocks = (nrows + ROWS_PER_BLOCK - 1) / ROWS_PER_BLOCK;  // 9375
    gle_fused<<<blocks, 256, 0, stream>>>(v, w_new, v_list, w_list,
                                          h, mass, T, out, nrows);
}